// Round 8
// baseline (1860.367 us; speedup 1.0000x reference)
//
#include <hip/hip_runtime.h>
#include <algorithm>

#define DT_F 0.02f
#define INV_R (1.0f / 0.1125f)

typedef __attribute__((ext_vector_type(8))) short short8;
typedef __attribute__((ext_vector_type(4))) float float4v;

static inline int cdiv(int a, int b) { return (a + b - 1) / b; }

__device__ __forceinline__ float sgnf(float v) {
    return (v > 0.f) ? 1.f : ((v < 0.f) ? -1.f : 0.f);
}

__device__ __forceinline__ unsigned short f2bf(float f) {
    union { float f; unsigned u; } v; v.f = f;
    return (unsigned short)((v.u + 0x7fffu + ((v.u >> 16) & 1u)) >> 16);
}
__device__ __forceinline__ float bf2f(unsigned short h) {
    union { unsigned u; float f; } v; v.u = ((unsigned)h) << 16;
    return v.f;
}

// Exact port of reference ball_to_cube (f32).
__device__ __forceinline__ void ball_to_cube_dev(float x, float y, float z,
                                                 float& ox, float& oy, float& oz) {
    const float eps = 1e-12f;
    float sq = x * x + y * y + z * z;
    float nrm = sqrtf(sq + eps);
    float xy2 = x * x + y * y;
    bool cap = 1.25f * z * z > xy2;
    float s_cap = sqrtf(3.f * nrm / (nrm + fabsf(z) + eps));
    float s_side = nrm / sqrtf(xy2 + eps);
    float s = cap ? s_cap : s_side;
    float xc = x * s, yc = y * s;
    float zc = cap ? sgnf(z) * nrm : 1.5f * z;
    if (!(sq > eps)) { xc = 0.f; yc = 0.f; zc = 0.f; }
    float rxy = sqrtf(xc * xc + yc * yc + eps);
    bool xbig = fabsf(yc) <= fabsf(xc);
    float dx = (fabsf(xc) > eps) ? xc : 1.f;
    float dy = (fabsf(yc) > eps) ? yc : 1.f;
    const float c4pi = 1.27323954473516276f;  // 4/pi
    float tx = sgnf(xc) * rxy, ty = sgnf(yc) * rxy;
    float xq = xbig ? tx : ty * c4pi * atanf(xc / dy);
    float yq = xbig ? tx * c4pi * atanf(yc / dx) : ty;
    if (!(xc * xc + yc * yc > eps)) { xq = 0.f; yq = 0.f; }
    ox = xq; oy = yq; oz = zc;
}

__global__ void prep_kernel(const float* __restrict__ pos, const float* __restrict__ vel,
                            int n, float* __restrict__ pos2, float* __restrict__ fl) {
    int i = blockIdx.x * blockDim.x + threadIdx.x;
    if (i >= n) return;
    float v0 = vel[i * 3 + 0], v1 = vel[i * 3 + 1], v2 = vel[i * 3 + 2];
    float u0 = v0, u1 = v1 + DT_F * (-9.81f), u2 = v2;
    pos2[i * 3 + 0] = pos[i * 3 + 0] + DT_F * (u0 + v0) * 0.5f;
    pos2[i * 3 + 1] = pos[i * 3 + 1] + DT_F * (u1 + v1) * 0.5f;
    pos2[i * 3 + 2] = pos[i * 3 + 2] + DT_F * (u2 + v2) * 0.5f;
    fl[i * 4 + 0] = 1.f;
    fl[i * 4 + 1] = u0;
    fl[i * 4 + 2] = u1;
    fl[i * 4 + 3] = u2;
}

__global__ void row_ptr_kernel(const int* __restrict__ q_idx, int E, int nq,
                               int* __restrict__ row_ptr) {
    int q = blockIdx.x * blockDim.x + threadIdx.x;
    if (q > nq) return;
    int lo = 0, hi = E;
    while (lo < hi) {
        int mid = (lo + hi) >> 1;
        if (q_idx[mid] < q) lo = mid + 1; else hi = mid;
    }
    row_ptr[q] = lo;
}

// Per-edge geometry once; ix clamped to [0,2] => 8 distinct corners.
// Outputs: wgt[e][8] (win folded), cells[e] = 8 packed cell bytes.
__global__ void edge_geom_kernel(const float* __restrict__ posq, const float* __restrict__ poss,
                                 const int* __restrict__ q_idx, const int* __restrict__ s_idx,
                                 int E, float* __restrict__ wgt, uint2* __restrict__ cells) {
    int e = blockIdx.x * blockDim.x + threadIdx.x;
    if (e >= E) return;
    int q = q_idx[e], s = s_idx[e];
    float dx = (poss[s * 3 + 0] - posq[q * 3 + 0]) * INV_R;
    float dy = (poss[s * 3 + 1] - posq[q * 3 + 1]) * INV_R;
    float dz = (poss[s * 3 + 2] - posq[q * 3 + 2]) * INV_R;
    float r2 = dx * dx + dy * dy + dz * dz;
    float w1 = 1.f - r2;
    float win = fminf(fmaxf(w1 * w1 * w1, 0.f), 1.f);
    float bx, by, bz;
    ball_to_cube_dev(dx, dy, dz, bx, by, bz);
    float gx = (bx + 1.f) * 1.5f, gy = (by + 1.f) * 1.5f, gz = (bz + 1.f) * 1.5f;
    int ix = min(max((int)floorf(gx), 0), 2);
    int iy = min(max((int)floorf(gy), 0), 2);
    int iz = min(max((int)floorf(gz), 0), 2);
    float fx = gx - (float)ix, fy = gy - (float)iy, fz = gz - (float)iz;
    float wv[8];
    unsigned int cl[8];
#pragma unroll
    for (int c = 0; c < 8; c++) {
        int cbx = (c >> 2) & 1, cby = (c >> 1) & 1, cbz = c & 1;
        int jx = ix + cbx, jy = iy + cby, jz = iz + cbz;
        cl[c] = (unsigned int)((jx * 4 + jy) * 4 + jz);
        wv[c] = win * (cbx ? fx : 1.f - fx) * (cby ? fy : 1.f - fy) * (cbz ? fz : 1.f - fz);
    }
    float4* wp = (float4*)(wgt + (size_t)e * 8);
    wp[0] = make_float4(wv[0], wv[1], wv[2], wv[3]);
    wp[1] = make_float4(wv[4], wv[5], wv[6], wv[7]);
    uint2 cp;
    cp.x = cl[0] | (cl[1] << 8) | (cl[2] << 16) | (cl[3] << 24);
    cp.y = cl[4] | (cl[5] << 8) | (cl[6] << 16) | (cl[7] << 24);
    cells[e] = cp;
}

// a_df = fl @ w_d0 + b_d0 -> x96[:, 64:96]
__global__ void dense0_kernel(const float* __restrict__ fl, const float* __restrict__ w,
                              const float* __restrict__ b, int n, float* __restrict__ x96) {
    int i = blockIdx.x * blockDim.x + threadIdx.x;
    if (i >= n * 32) return;
    int q = i >> 5, o = i & 31;
    float acc = b[o];
#pragma unroll
    for (int c = 0; c < 4; c++) acc += fl[q * 4 + c] * w[c * 32 + o];
    x96[(size_t)q * 96 + 64 + o] = acc;
}

// dst[q][0..31] = bf16(src[q][0..c-1]) zero-padded to 32.
__global__ void pad32_bf16(const float* __restrict__ src, int n, int c,
                           unsigned short* __restrict__ dst) {
    int i = blockIdx.x * blockDim.x + threadIdx.x;
    if (i >= n * 32) return;
    int q = i >> 5, k = i & 31;
    dst[i] = (k < c) ? f2bf(src[q * c + k]) : (unsigned short)0;
}

// h = bf16(relu(x)), flat n elems.
__global__ void relu_bf16_kernel(const float* __restrict__ x, int n,
                                 unsigned short* __restrict__ h) {
    int i = blockIdx.x * blockDim.x + threadIdx.x;
    if (i < n) h[i] = f2bf(fmaxf(x[i], 0.f));
}

// Layer-0 P weights: Wt[j=cell*32+o][k<32] = (k<CI ? w[cell][k][o] : 0); 2048 x 32 bf16.
__global__ void wtp0_kernel(const float* __restrict__ w, int CI,
                            unsigned short* __restrict__ Wt) {
    int i = blockIdx.x * blockDim.x + threadIdx.x;
    if (i >= 2048 * 32) return;
    int j = i >> 5, k = i & 31;
    int cell = j >> 5, o = j & 31;
    Wt[i] = (k < CI) ? f2bf(w[((size_t)cell * CI + k) * 32 + o]) : (unsigned short)0;
}

// L1/L2 P weights, half h: Wt[j=cl*64+o][k] = w_c[(h*32+cl)][k][o]; 2048 x K bf16.
__global__ void wtp_kernel(const float* __restrict__ wc, int K, int h,
                           unsigned short* __restrict__ Wt) {
    int i = blockIdx.x * blockDim.x + threadIdx.x;
    if (i >= 2048 * K) return;
    int j = i / K, k = i - j * K;
    int cl = j >> 6, o = j & 63;
    Wt[i] = f2bf(wc[(((size_t)(h * 32 + cl)) * K + k) * 64 + o]);
}

// Wt3[j=cell*3+o][k] = bf16(w_c3[cell][k][o]); 192 rows x 64 cols.
__global__ void wt3_kernel(const float* __restrict__ wc, unsigned short* __restrict__ Wt) {
    int i = blockIdx.x * blockDim.x + threadIdx.x;
    if (i >= 192 * 64) return;
    int j = i >> 6, k = i & 63;
    int cell = j / 3, o = j - cell * 3;
    Wt[i] = f2bf(wc[((size_t)cell * 64 + k) * 3 + o]);
}

// bf16 MFMA GEMM, bf16 store. A:[M][K] bf16; Wt:[N][K] bf16 (n-major); C:[M][ldc] bf16.
// grid (cdiv(M,64), N/64); 4 waves; K multiple of 32.
__global__ __launch_bounds__(256) void gemm_mfma_storeb(
    const unsigned short* __restrict__ A, const unsigned short* __restrict__ Wt,
    unsigned short* __restrict__ C, int M, int K, int ldc) {
    int wave = threadIdx.x >> 6, lane = threadIdx.x & 63;
    int m0 = blockIdx.x * 64;
    int n0 = blockIdx.y * 64 + wave * 16;
    int mrow = lane & 15, kq = lane >> 4;
    const unsigned short* Bp = Wt + (size_t)(n0 + mrow) * K;
    float4v acc[4] = {{0.f, 0.f, 0.f, 0.f}, {0.f, 0.f, 0.f, 0.f},
                      {0.f, 0.f, 0.f, 0.f}, {0.f, 0.f, 0.f, 0.f}};
    int r0 = min(m0 + mrow, M - 1);
    int r1 = min(m0 + 16 + mrow, M - 1);
    int r2 = min(m0 + 32 + mrow, M - 1);
    int r3 = min(m0 + 48 + mrow, M - 1);
    const unsigned short* A0 = A + (size_t)r0 * K;
    const unsigned short* A1 = A + (size_t)r1 * K;
    const unsigned short* A2 = A + (size_t)r2 * K;
    const unsigned short* A3 = A + (size_t)r3 * K;
    for (int k0 = 0; k0 < K; k0 += 32) {
        int kk = k0 + kq * 8;
        short8 b = *(const short8*)(Bp + kk);
        short8 a0 = *(const short8*)(A0 + kk);
        short8 a1 = *(const short8*)(A1 + kk);
        short8 a2 = *(const short8*)(A2 + kk);
        short8 a3 = *(const short8*)(A3 + kk);
        acc[0] = __builtin_amdgcn_mfma_f32_16x16x32_bf16(a0, b, acc[0], 0, 0, 0);
        acc[1] = __builtin_amdgcn_mfma_f32_16x16x32_bf16(a1, b, acc[1], 0, 0, 0);
        acc[2] = __builtin_amdgcn_mfma_f32_16x16x32_bf16(a2, b, acc[2], 0, 0, 0);
        acc[3] = __builtin_amdgcn_mfma_f32_16x16x32_bf16(a3, b, acc[3], 0, 0, 0);
    }
    int col = lane & 15, rq = lane >> 4;
#pragma unroll
    for (int mt = 0; mt < 4; mt++) {
#pragma unroll
        for (int r = 0; r < 4; r++) {
            int m = m0 + mt * 16 + rq * 4 + r;
            if (m < M) C[(size_t)m * ldc + n0 + col] = f2bf(acc[mt][r]);
        }
    }
}

// bf16 MFMA GEMM, f32 store (layer-3 P). Same layout as storeb.
__global__ __launch_bounds__(256) void gemm_mfma_store(
    const unsigned short* __restrict__ A, const unsigned short* __restrict__ Wt,
    float* __restrict__ C, int M, int K, int ldc) {
    int wave = threadIdx.x >> 6, lane = threadIdx.x & 63;
    int m0 = blockIdx.x * 64;
    int n0 = blockIdx.y * 64 + wave * 16;
    int mrow = lane & 15, kq = lane >> 4;
    const unsigned short* Bp = Wt + (size_t)(n0 + mrow) * K;
    float4v acc[4] = {{0.f, 0.f, 0.f, 0.f}, {0.f, 0.f, 0.f, 0.f},
                      {0.f, 0.f, 0.f, 0.f}, {0.f, 0.f, 0.f, 0.f}};
    int r0 = min(m0 + mrow, M - 1);
    int r1 = min(m0 + 16 + mrow, M - 1);
    int r2 = min(m0 + 32 + mrow, M - 1);
    int r3 = min(m0 + 48 + mrow, M - 1);
    const unsigned short* A0 = A + (size_t)r0 * K;
    const unsigned short* A1 = A + (size_t)r1 * K;
    const unsigned short* A2 = A + (size_t)r2 * K;
    const unsigned short* A3 = A + (size_t)r3 * K;
    for (int k0 = 0; k0 < K; k0 += 32) {
        int kk = k0 + kq * 8;
        short8 b = *(const short8*)(Bp + kk);
        short8 a0 = *(const short8*)(A0 + kk);
        short8 a1 = *(const short8*)(A1 + kk);
        short8 a2 = *(const short8*)(A2 + kk);
        short8 a3 = *(const short8*)(A3 + kk);
        acc[0] = __builtin_amdgcn_mfma_f32_16x16x32_bf16(a0, b, acc[0], 0, 0, 0);
        acc[1] = __builtin_amdgcn_mfma_f32_16x16x32_bf16(a1, b, acc[1], 0, 0, 0);
        acc[2] = __builtin_amdgcn_mfma_f32_16x16x32_bf16(a2, b, acc[2], 0, 0, 0);
        acc[3] = __builtin_amdgcn_mfma_f32_16x16x32_bf16(a3, b, acc[3], 0, 0, 0);
    }
    int col = lane & 15, rq = lane >> 4;
#pragma unroll
    for (int mt = 0; mt < 4; mt++) {
#pragma unroll
        for (int r = 0; r < 4; r++) {
            int m = m0 + mt * 16 + rq * 4 + r;
            if (m < M) C[(size_t)m * ldc + n0 + col] = acc[mt][r];
        }
    }
}

// L0 gather-reduce: x96[q][off+o] = sum_e sum_corners w_c * P[s][cell*32+o].
// Wave per q; lane = (sub half) * 32 + o; sub-half handles corners {sub,sub+2,sub+4,sub+6};
// merged by shfl at the end. P loads: 32 lanes x 2B contiguous = coalesced.
__global__ __launch_bounds__(256) void reduce32_kernel(
    const unsigned short* __restrict__ P, const float* __restrict__ wgt,
    const uint2* __restrict__ cells, const int* __restrict__ s_idx,
    const int* __restrict__ row_ptr, int n, int off, float* __restrict__ x96) {
    int wave = threadIdx.x >> 6, lane = threadIdx.x & 63;
    int q = blockIdx.x * 4 + wave;
    if (q >= n) return;
    int o = lane & 31, sub = lane >> 5;
    float a0 = 0.f, a1 = 0.f;
    int e0 = row_ptr[q], e1 = row_ptr[q + 1];
    if (e0 < e1) {
        int s = s_idx[e0];
        uint2 cp = cells[e0];
        const float4* wp = (const float4*)(wgt + (size_t)e0 * 8);
        float4 wa = wp[0], wb = wp[1];
        for (int e = e0; e < e1; e++) {
            int en = (e + 1 < e1) ? e + 1 : e;
            int sn = s_idx[en];
            uint2 cpn = cells[en];
            const float4* wpn = (const float4*)(wgt + (size_t)en * 8);
            float4 wan = wpn[0], wbn = wpn[1];
            const unsigned short* Ps = P + (size_t)s * 2048 + o;
            float w0 = sub ? wa.y : wa.x;
            float w1 = sub ? wa.w : wa.z;
            float w2 = sub ? wb.y : wb.x;
            float w3 = sub ? wb.w : wb.z;
            unsigned c0 = (cp.x >> (sub * 8)) & 255u;
            unsigned c1 = (cp.x >> (16 + sub * 8)) & 255u;
            unsigned c2 = (cp.y >> (sub * 8)) & 255u;
            unsigned c3 = (cp.y >> (16 + sub * 8)) & 255u;
            a0 += w0 * bf2f(Ps[c0 * 32]);
            a1 += w1 * bf2f(Ps[c1 * 32]);
            a0 += w2 * bf2f(Ps[c2 * 32]);
            a1 += w3 * bf2f(Ps[c3 * 32]);
            s = sn; cp = cpn; wa = wan; wb = wbn;
        }
    }
    float a = a0 + a1;
    a += __shfl_xor(a, 32);
    if (lane < 32) x96[(size_t)q * 96 + off + o] = a;
}

// L1/L2 gather-reduce, half pass. Wave per q, lane = output channel (64).
// pass half=0: acc = bias + dense(h@wd) + corners with cell<32;
// pass half=1: acc = y + corners with cell>=32 (+resid), store.
// Corner-in-half test is wave-uniform => skipped corners skip their loads.
__global__ __launch_bounds__(256) void reduce64_kernel(
    const unsigned short* __restrict__ P, const float* __restrict__ wgt,
    const uint2* __restrict__ cells, const int* __restrict__ s_idx,
    const int* __restrict__ row_ptr, const unsigned short* __restrict__ hq, int K,
    const float* __restrict__ wd, const float* __restrict__ bias,
    const float* __restrict__ resid, int half, int n, float* __restrict__ y) {
    int wave = threadIdx.x >> 6, lane = threadIdx.x & 63;
    int q = blockIdx.x * 4 + wave;
    if (q >= n) return;
    float acc0, acc1 = 0.f;
    if (half == 0) {
        acc0 = bias[lane];
        const unsigned short* h = hq + (size_t)q * K;
        for (int k = 0; k < K; k++) acc0 += bf2f(h[k]) * wd[k * 64 + lane];
    } else {
        acc0 = y[(size_t)q * 64 + lane];
    }
    unsigned hsel = (unsigned)half;
    int e0 = row_ptr[q], e1 = row_ptr[q + 1];
    if (e0 < e1) {
        int s = s_idx[e0];
        uint2 cp = cells[e0];
        const float4* wp = (const float4*)(wgt + (size_t)e0 * 8);
        float4 wa = wp[0], wb = wp[1];
        for (int e = e0; e < e1; e++) {
            int en = (e + 1 < e1) ? e + 1 : e;
            int sn = s_idx[en];
            uint2 cpn = cells[en];
            const float4* wpn = (const float4*)(wgt + (size_t)en * 8);
            float4 wan = wpn[0], wbn = wpn[1];
            const unsigned short* Ps = P + (size_t)s * 2048 + lane;
            unsigned c;
            c = cp.x & 255u;
            if ((c >> 5) == hsel) acc0 += wa.x * bf2f(Ps[(c & 31u) * 64]);
            c = (cp.x >> 8) & 255u;
            if ((c >> 5) == hsel) acc1 += wa.y * bf2f(Ps[(c & 31u) * 64]);
            c = (cp.x >> 16) & 255u;
            if ((c >> 5) == hsel) acc0 += wa.z * bf2f(Ps[(c & 31u) * 64]);
            c = (cp.x >> 24) & 255u;
            if ((c >> 5) == hsel) acc1 += wa.w * bf2f(Ps[(c & 31u) * 64]);
            c = cp.y & 255u;
            if ((c >> 5) == hsel) acc0 += wb.x * bf2f(Ps[(c & 31u) * 64]);
            c = (cp.y >> 8) & 255u;
            if ((c >> 5) == hsel) acc1 += wb.y * bf2f(Ps[(c & 31u) * 64]);
            c = (cp.y >> 16) & 255u;
            if ((c >> 5) == hsel) acc0 += wb.z * bf2f(Ps[(c & 31u) * 64]);
            c = (cp.y >> 24) & 255u;
            if ((c >> 5) == hsel) acc1 += wb.w * bf2f(Ps[(c & 31u) * 64]);
            s = sn; cp = cpn; wa = wan; wb = wbn;
        }
    }
    float a = acc0 + acc1;
    if (resid != nullptr && half == 1) a += resid[(size_t)q * 64 + lane];
    y[(size_t)q * 64 + lane] = a;
}

// Layer 3: y3[q] = sum_edges sum_corners w * P[s][cell*3+o] + relu(x64b[q])@w_d3 + b_d3.
__global__ __launch_bounds__(256) void conv3_reduce(
    const float* __restrict__ P,
    const float* __restrict__ wgt, const uint2* __restrict__ cells,
    const int* __restrict__ s_idx, const int* __restrict__ row_ptr,
    const unsigned short* __restrict__ hq, const float* __restrict__ wd3,
    const float* __restrict__ b3, int n, float* __restrict__ y3) {
    int wave = threadIdx.x >> 6, lane = threadIdx.x & 63;
    int q = blockIdx.x * 4 + wave;
    if (q >= n) return;
    float a0 = 0.f, a1 = 0.f, a2 = 0.f;
    int e0 = row_ptr[q], e1 = row_ptr[q + 1];
    for (int e = e0 + lane; e < e1; e += 64) {
        int s = s_idx[e];
        uint2 cp = cells[e];
        const float4* wp = (const float4*)(wgt + (size_t)e * 8);
        float4 wa = wp[0], wb = wp[1];
        const float* Ps = P + (size_t)s * 192;
        float wv[8] = {wa.x, wa.y, wa.z, wa.w, wb.x, wb.y, wb.z, wb.w};
#pragma unroll
        for (int c = 0; c < 8; c++) {
            unsigned word = (c < 4) ? cp.x : cp.y;
            int cell = (int)((word >> ((c & 3) * 8)) & 255u);
            const float* pc = Ps + cell * 3;
            a0 += wv[c] * pc[0];
            a1 += wv[c] * pc[1];
            a2 += wv[c] * pc[2];
        }
    }
    float hv = bf2f(hq[(size_t)q * 64 + lane]);
    a0 += hv * wd3[lane * 3 + 0];
    a1 += hv * wd3[lane * 3 + 1];
    a2 += hv * wd3[lane * 3 + 2];
#pragma unroll
    for (int off = 32; off > 0; off >>= 1) {
        a0 += __shfl_xor(a0, off);
        a1 += __shfl_xor(a1, off);
        a2 += __shfl_xor(a2, off);
    }
    if (lane == 0) {
        y3[(size_t)q * 3 + 0] = a0 + b3[0];
        y3[(size_t)q * 3 + 1] = a1 + b3[1];
        y3[(size_t)q * 3 + 2] = a2 + b3[2];
    }
}

__global__ void final_kernel(const float* __restrict__ pos, const float* __restrict__ pos2,
                             const float* __restrict__ y3, int n, float* __restrict__ out) {
    int i = blockIdx.x * blockDim.x + threadIdx.x;
    if (i >= n * 3) return;
    float pn = pos2[i] + y3[i] * (1.f / 128.f);
    out[i] = pn;
    out[n * 3 + i] = (pn - pos[i]) * (1.f / DT_F);
}

extern "C" void kernel_launch(void* const* d_in, const int* in_sizes, int n_in,
                              void* d_out, int out_size, void* d_ws, size_t ws_size,
                              hipStream_t stream) {
    const float* pos       = (const float*)d_in[0];
    const float* vel       = (const float*)d_in[1];
    const float* box       = (const float*)d_in[2];
    const float* box_feats = (const float*)d_in[3];
    const int*   ff_q      = (const int*)d_in[4];
    const int*   ff_s      = (const int*)d_in[5];
    const int*   fo_q      = (const int*)d_in[6];
    const int*   fo_s      = (const int*)d_in[7];
    const float* w_cf0     = (const float*)d_in[8];
    const float* w_co0     = (const float*)d_in[9];
    const float* w_d0      = (const float*)d_in[10];
    const float* b_d0      = (const float*)d_in[11];
    const float* w_c1      = (const float*)d_in[12];
    const float* w_d1      = (const float*)d_in[13];
    const float* b_d1      = (const float*)d_in[14];
    const float* w_c2      = (const float*)d_in[15];
    const float* w_d2      = (const float*)d_in[16];
    const float* b_d2      = (const float*)d_in[17];
    const float* w_c3      = (const float*)d_in[18];
    const float* w_d3      = (const float*)d_in[19];
    const float* b_d3      = (const float*)d_in[20];
    float* out = (float*)d_out;

    int n   = in_sizes[0] / 3;
    int nb  = in_sizes[2] / 3;
    int Eff = in_sizes[4];
    int Efo = in_sizes[6];

    float* base = (float*)d_ws;
    size_t off = 0;
    auto alloc = [&](size_t nf) { float* p = base + off; off += (nf + 3) & ~(size_t)3; return p; };
    float* pos2  = alloc((size_t)n * 3);
    float* fl    = alloc((size_t)n * 4);
    float* x96   = alloc((size_t)n * 96);
    float* x64a  = alloc((size_t)n * 64);
    float* x64b  = alloc((size_t)n * 64);
    float* y3    = alloc((size_t)n * 3);
    int* rp_ff   = (int*)alloc((size_t)n + 1);
    int* rp_fo   = (int*)alloc((size_t)n + 1);
    unsigned short* flb = (unsigned short*)alloc((size_t)n * 16);      // [n][32] bf16
    unsigned short* bxb = (unsigned short*)alloc((size_t)nb * 16);     // [nb][32] bf16
    unsigned short* xbr = (unsigned short*)alloc((size_t)n * 48);      // [n][96] bf16 max
    unsigned short* WtP = (unsigned short*)alloc((size_t)2048 * 96 / 2);
    unsigned short* Wt3 = (unsigned short*)alloc((size_t)192 * 64 / 2);
    float* P3    = alloc((size_t)n * 192);
    float* wgt_ff = alloc((size_t)Eff * 8);
    uint2* cl_ff  = (uint2*)alloc((size_t)Eff * 2);
    float* wgt_fo = alloc((size_t)Efo * 8);
    uint2* cl_fo  = (uint2*)alloc((size_t)Efo * 2);
    unsigned short* Pb = (unsigned short*)alloc((size_t)n * 1024);     // [n][2048] bf16

    // --- prep, CSR, edge geometry (once) ---
    prep_kernel<<<cdiv(n, 256), 256, 0, stream>>>(pos, vel, n, pos2, fl);
    row_ptr_kernel<<<cdiv(n + 1, 256), 256, 0, stream>>>(ff_q, Eff, n, rp_ff);
    row_ptr_kernel<<<cdiv(n + 1, 256), 256, 0, stream>>>(fo_q, Efo, n, rp_fo);
    edge_geom_kernel<<<cdiv(Eff, 256), 256, 0, stream>>>(pos2, pos2, ff_q, ff_s, Eff, wgt_ff, cl_ff);
    edge_geom_kernel<<<cdiv(Efo, 256), 256, 0, stream>>>(pos2, box, fo_q, fo_s, Efo, wgt_fo, cl_fo);

    pad32_bf16<<<cdiv(n * 32, 256), 256, 0, stream>>>(fl, n, 4, flb);
    pad32_bf16<<<cdiv(nb * 32, 256), 256, 0, stream>>>(box_feats, nb, 3, bxb);
    dense0_kernel<<<cdiv(n * 32, 256), 256, 0, stream>>>(fl, w_d0, b_d0, n, x96);

    // --- layer 0 fluid: P = fl @ w_cf0 (K padded to 32), gather-reduce -> x96[:,32:64] ---
    wtp0_kernel<<<cdiv(2048 * 32, 256), 256, 0, stream>>>(w_cf0, 4, WtP);
    gemm_mfma_storeb<<<dim3(cdiv(n, 64), 32), 256, 0, stream>>>(flb, WtP, Pb, n, 32, 2048);
    reduce32_kernel<<<cdiv(n, 4), 256, 0, stream>>>(Pb, wgt_ff, cl_ff, ff_s, rp_ff, n, 32, x96);

    // --- layer 0 box: P = box_feats @ w_co0, gather-reduce -> x96[:,0:32] ---
    wtp0_kernel<<<cdiv(2048 * 32, 256), 256, 0, stream>>>(w_co0, 3, WtP);
    gemm_mfma_storeb<<<dim3(cdiv(nb, 64), 32), 256, 0, stream>>>(bxb, WtP, Pb, nb, 32, 2048);
    reduce32_kernel<<<cdiv(n, 4), 256, 0, stream>>>(Pb, wgt_fo, cl_fo, fo_s, rp_fo, n, 0, x96);

    // --- layer 1: 96 -> 64, two cell-halves ---
    relu_bf16_kernel<<<cdiv(n * 96, 256), 256, 0, stream>>>(x96, n * 96, xbr);
    for (int h = 0; h < 2; h++) {
        wtp_kernel<<<cdiv(2048 * 96, 256), 256, 0, stream>>>(w_c1, 96, h, WtP);
        gemm_mfma_storeb<<<dim3(cdiv(n, 64), 32), 256, 0, stream>>>(xbr, WtP, Pb, n, 96, 2048);
        reduce64_kernel<<<cdiv(n, 4), 256, 0, stream>>>(
            Pb, wgt_ff, cl_ff, ff_s, rp_ff, xbr, 96, w_d1, b_d1, nullptr, h, n, x64a);
    }

    // --- layer 2: 64 -> 64, residual, two cell-halves ---
    relu_bf16_kernel<<<cdiv(n * 64, 256), 256, 0, stream>>>(x64a, n * 64, xbr);
    for (int h = 0; h < 2; h++) {
        wtp_kernel<<<cdiv(2048 * 64, 256), 256, 0, stream>>>(w_c2, 64, h, WtP);
        gemm_mfma_storeb<<<dim3(cdiv(n, 64), 32), 256, 0, stream>>>(xbr, WtP, Pb, n, 64, 2048);
        reduce64_kernel<<<cdiv(n, 4), 256, 0, stream>>>(
            Pb, wgt_ff, cl_ff, ff_s, rp_ff, xbr, 64, w_d2, b_d2, x64a, h, n, x64b);
    }

    // --- layer 3: 64 -> 3 ---
    relu_bf16_kernel<<<cdiv(n * 64, 256), 256, 0, stream>>>(x64b, n * 64, xbr);
    wt3_kernel<<<cdiv(192 * 64, 256), 256, 0, stream>>>(w_c3, Wt3);
    gemm_mfma_store<<<dim3(cdiv(n, 64), 3), 256, 0, stream>>>(xbr, Wt3, P3, n, 64, 192);
    conv3_reduce<<<cdiv(n, 4), 256, 0, stream>>>(
        P3, wgt_ff, cl_ff, ff_s, rp_ff, xbr, w_d3, b_d3, n, y3);

    final_kernel<<<cdiv(n * 3, 256), 256, 0, stream>>>(pos, pos2, y3, n, out);
}